// Round 1
// 494.141 us; speedup vs baseline: 1.4839x; 1.4839x over previous
//
#include <hip/hip_runtime.h>

// Problem constants
#define N_NODES 4096
#define E_TOT   12288
#define F_NODE  64
#define F_EDGE  16
#define HDIM    128
#define NLAYER  4
#define NGRAPH  256

typedef _Float16 half8 __attribute__((ext_vector_type(8)));
typedef float    f32x4 __attribute__((ext_vector_type(4)));

// ---------------------------------------------------------------------------
// Repack e2_w (+e2_b as a 129th K-chunk) into f16 "fragment-major" layout:
// W2F[((l*129 + k)*32 + chunk)*512 + lane*8 + j]
//   chunk = hc*8 + ot ;  h = hc*32 + (lane>>4)*8 + j ;  o = ot*16 + (lane&15)
// so that global_load_lds(16B/lane) deposits ready-to-use MFMA B fragments.
// ---------------------------------------------------------------------------
__global__ void k_prep_w2(const float* __restrict__ e2w, const float* __restrict__ e2b,
                          _Float16* __restrict__ W2F)
{
    int t = blockIdx.x * 256 + threadIdx.x;
    const int PER_L = 129 * 16384;
    if (t >= NLAYER * PER_L) return;
    int l   = t / PER_L;
    int r   = t - l * PER_L;
    int k   = r >> 14;          // 0..128 (128 = bias chunk)
    int rem = r & 16383;
    int chunk = rem >> 9;
    int lane  = (rem >> 3) & 63;
    int j     = rem & 7;
    int hc = chunk >> 3, ot = chunk & 7;
    int h  = hc * 32 + (lane >> 4) * 8 + j;
    int o  = ot * 16 + (lane & 15);
    float v;
    if (k < 128) v = e2w[((size_t)(l * 128 + k)) * 16384 + h * 128 + o];
    else         v = e2b[(size_t)l * 16384 + h * 128 + o];
    W2F[t] = (_Float16)v;
}

// h = x @ node_w + node_b  (also f16 copy for the gather path)
__global__ __launch_bounds__(128)
void k_node_enc(const float* __restrict__ x, const float* __restrict__ nw,
                const float* __restrict__ nb, float* __restrict__ h,
                _Float16* __restrict__ hf)
{
    __shared__ float xl[F_NODE];
    int n = blockIdx.x, o = threadIdx.x;
    if (o < F_NODE) xl[o] = x[(size_t)n * F_NODE + o];
    __syncthreads();
    float acc = nb[o];
#pragma unroll 8
    for (int f = 0; f < F_NODE; ++f) acc += xl[f] * nw[f * HDIM + o];
    h [(size_t)n * HDIM + o] = acc;
    hf[(size_t)n * HDIM + o] = (_Float16)acc;
}

__global__ void k_deg(const int* __restrict__ dst, int* __restrict__ deg)
{
    int e = blockIdx.x * 256 + threadIdx.x;
    if (e < E_TOT) atomicAdd(&deg[dst[e]], 1);
}

__global__ void k_invd(const int* __restrict__ deg, float* __restrict__ invd)
{
    int n = blockIdx.x * 256 + threadIdx.x;
    if (n < N_NODES) invd[n] = deg[n] > 0 ? 1.0f / (float)deg[n] : 0.0f;
}

// ef = relu(edge_attr @ e1_w[l] + e1_b[l]) stored f16 [E][136] (stride 136 for
// 16B-aligned rows; col128 = 1.0 bias chunk, cols 129..135 unused)
#define EF_STRIDE 136
__global__ __launch_bounds__(128)
void k_edge_mlp(const float* __restrict__ ea, const float* __restrict__ w1,
                const float* __restrict__ b1, _Float16* __restrict__ efg)
{
    __shared__ float al[F_EDGE];
    int e = blockIdx.x, j = threadIdx.x;
    if (j < F_EDGE) al[j] = ea[(size_t)e * F_EDGE + j];
    __syncthreads();
    float acc = b1[j];
#pragma unroll
    for (int f = 0; f < F_EDGE; ++f) acc += al[f] * w1[f * HDIM + j];
    acc = fmaxf(acc, 0.f);
    efg[(size_t)e * EF_STRIDE + j] = (_Float16)acc;
    if (j == 0) efg[(size_t)e * EF_STRIDE + 128] = (_Float16)1.0f;
}

// ---------------------------------------------------------------------------
// msg[e,o] = sum_k ef[e,k] * (h[src[e],:] @ W2[k,:,:]) ; atomic scatter-add
// into agg[dst[e]].
// v2: BM=256 edges/block, 8 waves (512 thr) = 2 waves/SIMD.  k-split x4 so
// grid stays 192 blocks and each block streams only ~1/4 of W2 (4x less
// cache traffic; partial sums merge via the atomics).  B triple-buffered via
// global_load_lds with counted vmcnt (prefetch distance 2).  Only the local
// k-slice of ef is staged (vectorized).  XCD swizzle groups same-k-slice
// blocks on an XCD so the 1.06 MB B slice is L2-resident.
// ---------------------------------------------------------------------------
__global__ __launch_bounds__(512, 2)
void k_msg(const _Float16* __restrict__ W2L,   // layer base: [129][32][512] f16
           const _Float16* __restrict__ efg,   // [E][136] f16
           const _Float16* __restrict__ hf,    // [N][128] f16
           const int* __restrict__ srcIdx,
           const int* __restrict__ dstIdx,
           float* __restrict__ agg)
{
    __shared__ _Float16 Bb[3][16384];   // 3 x 32 KB B-chunk triple buffer
    __shared__ _Float16 efs[256][40];   // local k-slice of ef (<=33 cols + pad)

    const int tid  = threadIdx.x;
    const int lane = tid & 63;
    const int w    = tid >> 6;          // wave 0..7
    const int rq   = w >> 1;            // row-quarter: 64 edges
    const int ch   = w & 1;             // col-half: 64 outputs
    const int lhi  = lane >> 4;         // 0..3
    const int llo  = lane & 15;

    // XCD-grouped decode: blocks with the same k-slice land on the same XCD
    // (bx%8 -> XCD round-robin): bx = pair*8 + ks*2 + (tile&1)
    const int bx    = blockIdx.x;
    const int ks    = (bx >> 1) & 3;
    const int tile  = (bx >> 3) * 2 + (bx & 1);
    const int e0    = tile * 256;
    const int kbase = (129 * ks) >> 2;                    // 0,32,64,96
    const int kcnt  = ((129 * (ks + 1)) >> 2) - kbase;    // 32,32,32,33

    // stage ef k-slice (256 rows x 40 f16), vectorized half8
    {
        int r = tid >> 1, h2 = tid & 1;
        const half8* sp = (const half8*)(efg + (size_t)(e0 + r) * EF_STRIDE + kbase);
        half8* dp = (half8*)&efs[r][0];
        if (h2 == 0) { dp[0] = sp[0]; dp[1] = sp[1]; dp[2] = sp[2]; }
        else         { dp[3] = sp[3]; dp[4] = sp[4]; }
    }

    // h_src fragments (this wave's 64 rows) resident in registers, f16
    half8 hs[4][4];
#pragma unroll
    for (int rf = 0; rf < 4; ++rf) {
        int s = srcIdx[e0 + rq * 64 + rf * 16 + llo];
        const _Float16* hp = hf + (size_t)s * HDIM + lhi * 8;
#pragma unroll
        for (int hc = 0; hc < 4; ++hc)
            hs[rf][hc] = *(const half8*)(hp + hc * 32);
    }

    // drain all register-bound memory BEFORE issuing stages, so the compiler
    // never needs an in-loop vmcnt for hs/efs.
    asm volatile("s_waitcnt vmcnt(0) lgkmcnt(0)" ::: "memory");

    // per-k B chunk = 32 KB; wave w stages f16 [w*2048, w*2048+2048) = 4 x 1KB
    auto STAGE = [&](int kg, int buf) {
        const _Float16* g = W2L + (size_t)kg * 16384 + w * 2048 + lane * 8;
        _Float16* lp = &Bb[buf][w * 2048];
#pragma unroll
        for (int i = 0; i < 4; ++i)
            __builtin_amdgcn_global_load_lds(
                (const __attribute__((address_space(1))) void*)(g + i * 512),
                (__attribute__((address_space(3))) void*)(lp + i * 512), 16, 0, 0);
    };

    STAGE(kbase + 0, 0);
    STAGE(kbase + 1, 1);

    f32x4 acc[4][4];
#pragma unroll
    for (int rf = 0; rf < 4; ++rf)
#pragma unroll
        for (int cf = 0; cf < 4; ++cf)
#pragma unroll
            for (int d = 0; d < 4; ++d) acc[rf][cf][d] = 0.f;

    int cur = 0, stg = 2;
    for (int kk = 0; kk < kcnt; ++kk) {
        // barrier1: all waves done reading Bb[stg] (iter kk-1) + (kk==0) efs ready
        asm volatile("" ::: "memory");
        __builtin_amdgcn_s_barrier();
        asm volatile("" ::: "memory");
        if (kk + 2 < kcnt) {
            STAGE(kbase + kk + 2, stg);
            // wait for own stage(kk) 4 loads; stages kk+1,kk+2 (8) stay in flight
            asm volatile("s_waitcnt vmcnt(8)" ::: "memory");
        } else if (kk + 1 < kcnt) {
            asm volatile("s_waitcnt vmcnt(4)" ::: "memory");
        } else {
            asm volatile("s_waitcnt vmcnt(0)" ::: "memory");
        }
        asm volatile("" ::: "memory");
        __builtin_amdgcn_s_barrier();
        asm volatile("" ::: "memory");

        // ef scalars for this k (16 rows per rf, broadcast across lhi groups)
        _Float16 efv[4];
        const _Float16* erow = &efs[rq * 64 + llo][kk];
#pragma unroll
        for (int rf = 0; rf < 4; ++rf) efv[rf] = erow[rf * 16 * 40];

        const _Float16* bb = &Bb[cur][ch * 2048 + lane * 8];
#pragma unroll
        for (int hc = 0; hc < 4; ++hc) {
            half8 bfr[4];
#pragma unroll
            for (int cf = 0; cf < 4; ++cf)       // chunk = hc*8 + ch*4 + cf
                bfr[cf] = *(const half8*)(bb + hc * 4096 + cf * 512);
#pragma unroll
            for (int rf = 0; rf < 4; ++rf) {
                half8 av = hs[rf][hc] * efv[rf];   // v_pk_mul_f16
#pragma unroll
                for (int cf = 0; cf < 4; ++cf)
                    acc[rf][cf] = __builtin_amdgcn_mfma_f32_16x16x32_f16(
                        av, bfr[cf], acc[rf][cf], 0, 0, 0);
            }
        }
        cur = cur == 2 ? 0 : cur + 1;
        stg = stg == 2 ? 0 : stg + 1;
    }

    // epilogue: scatter-add partial msg into agg[dst]
    // C/D layout: col=lane&15, row=(lane>>4)*4+reg
#pragma unroll
    for (int rf = 0; rf < 4; ++rf) {
#pragma unroll
        for (int r = 0; r < 4; ++r) {
            int row = rq * 64 + rf * 16 + lhi * 4 + r;
            int d   = dstIdx[e0 + row];
#pragma unroll
            for (int cf = 0; cf < 4; ++cf) {
                int o = ch * 64 + cf * 16 + llo;
                atomicAdd(&agg[(size_t)d * HDIM + o], acc[rf][cf][r]);
            }
        }
    }
}

// out = agg*inv_deg + h @ root_w[l] + conv_b[l]   (16 rows per block)
__global__ __launch_bounds__(128)
void k_out(const float* __restrict__ agg, const float* __restrict__ invd,
           const float* __restrict__ h, const float* __restrict__ rw,
           const float* __restrict__ cb, float* __restrict__ outb)
{
    __shared__ float hl[16][HDIM];
    int n0 = blockIdx.x * 16, o = threadIdx.x;
    for (int r = 0; r < 16; ++r) hl[r][o] = h[(size_t)(n0 + r) * HDIM + o];
    __syncthreads();
    float acc[16];
    float cbv = cb[o];
#pragma unroll
    for (int r = 0; r < 16; ++r)
        acc[r] = agg[(size_t)(n0 + r) * HDIM + o] * invd[n0 + r] + cbv;
    for (int hh = 0; hh < HDIM; ++hh) {
        float wv = rw[hh * HDIM + o];
#pragma unroll
        for (int r = 0; r < 16; ++r) acc[r] += hl[r][hh] * wv;
    }
#pragma unroll
    for (int r = 0; r < 16; ++r) outb[(size_t)(n0 + r) * HDIM + o] = acc[r];
}

// per-channel batch stats (biased var) -> mu, rsig
__global__ __launch_bounds__(256)
void k_bn_stats(const float* __restrict__ outb, float* __restrict__ mu,
                float* __restrict__ rsig)
{
    __shared__ float s1[256], s2[256];
    int c = blockIdx.x, t = threadIdx.x;
    float a = 0.f, b = 0.f;
    for (int n = t; n < N_NODES; n += 256) {
        float v = outb[(size_t)n * HDIM + c];
        a += v; b += v * v;
    }
    s1[t] = a; s2[t] = b;
    __syncthreads();
    for (int s = 128; s > 0; s >>= 1) {
        if (t < s) { s1[t] += s1[t + s]; s2[t] += s2[t + s]; }
        __syncthreads();
    }
    if (t == 0) {
        float m   = s1[0] / (float)N_NODES;
        float var = s2[0] / (float)N_NODES - m * m;
        mu[c]   = m;
        rsig[c] = rsqrtf(var + 1e-5f);
    }
}

// h += relu(bn(out));  also refresh f16 copy
__global__ void k_bn_apply(const float* __restrict__ outb, const float* __restrict__ mu,
                           const float* __restrict__ rsig, const float* __restrict__ g,
                           const float* __restrict__ b, float* __restrict__ h,
                           _Float16* __restrict__ hf)
{
    int i = blockIdx.x * 256 + threadIdx.x;   // < N*128
    int o = i & (HDIM - 1);
    float v  = (outb[i] - mu[o]) * rsig[o] * g[o] + b[o];
    float hn = h[i] + fmaxf(v, 0.f);
    h[i]  = hn;
    hf[i] = (_Float16)hn;
}

__global__ __launch_bounds__(128)
void k_pool(const float* __restrict__ h, const int* __restrict__ batch,
            float* __restrict__ pooled, int* __restrict__ cnt)
{
    int n = blockIdx.x, c = threadIdx.x;
    int g = batch[n];
    atomicAdd(&pooled[(size_t)g * HDIM + c], h[(size_t)n * HDIM + c]);
    if (c == 0) atomicAdd(&cnt[g], 1);
}

__global__ __launch_bounds__(128)
void k_head(const float* __restrict__ pooled, const int* __restrict__ cnt,
            const float* __restrict__ w1, const float* __restrict__ b1,
            const float* __restrict__ w2, const float* __restrict__ b2,
            float* __restrict__ y)
{
    __shared__ float pl[HDIM];
    __shared__ float red[HDIM];
    int g = blockIdx.x, o = threadIdx.x;
    float ic = 1.0f / (float)max(cnt[g], 1);
    pl[o] = pooled[(size_t)g * HDIM + o] * ic;
    __syncthreads();
    float t = b1[o];
#pragma unroll 8
    for (int hh = 0; hh < HDIM; ++hh) t += pl[hh] * w1[hh * HDIM + o];
    t = fmaxf(t, 0.f);
    red[o] = t * w2[o];
    __syncthreads();
    for (int s = 64; s > 0; s >>= 1) {
        if (o < s) red[o] += red[o + s];
        __syncthreads();
    }
    if (o == 0) y[g] = red[0] + b2[0];
}

// ---------------------------------------------------------------------------
extern "C" void kernel_launch(void* const* d_in, const int* in_sizes, int n_in,
                              void* d_out, int out_size, void* d_ws, size_t ws_size,
                              hipStream_t stream)
{
    const float* x      = (const float*)d_in[0];
    const int*   ei     = (const int*)  d_in[1];
    const float* ea     = (const float*)d_in[2];
    const int*   batch  = (const int*)  d_in[3];
    const float* node_w = (const float*)d_in[4];
    const float* node_b = (const float*)d_in[5];
    const float* e1w    = (const float*)d_in[6];
    const float* e1b    = (const float*)d_in[7];
    const float* e2w    = (const float*)d_in[8];
    const float* e2b    = (const float*)d_in[9];
    const float* rw     = (const float*)d_in[10];
    const float* cb     = (const float*)d_in[11];
    const float* bng    = (const float*)d_in[12];
    const float* bnb    = (const float*)d_in[13];
    const float* hw1    = (const float*)d_in[14];
    const float* hb1    = (const float*)d_in[15];
    const float* hw2    = (const float*)d_in[16];
    const float* hb2    = (const float*)d_in[17];
    float* y = (float*)d_out;

    // workspace carve-up (~27.8 MB, all 256B-aligned chunks)
    char* ws = (char*)d_ws;
    _Float16* W2F  = (_Float16*)ws; ws += 16908288;  // 4*129*16384 f16
    float*    h    = (float*)ws;    ws += 2097152;
    _Float16* hf   = (_Float16*)ws; ws += 1048576;
    _Float16* efg  = (_Float16*)ws; ws += 3342336;   // E*136 f16
    float*    agg  = (float*)ws;    ws += 2097152;
    float*    outb = (float*)ws;    ws += 2097152;
    int*      deg  = (int*)ws;      ws += 16384;
    float*    invd = (float*)ws;    ws += 16384;
    float*    mu   = (float*)ws;    ws += 512;
    float*    rsig = (float*)ws;    ws += 512;
    float*    pooled = (float*)ws;  ws += 131072;
    int*      cnt  = (int*)ws;      ws += 1024;

    const int* src = ei;
    const int* dst = ei + E_TOT;

    k_prep_w2<<<33024, 256, 0, stream>>>(e2w, e2b, W2F);
    k_node_enc<<<N_NODES, 128, 0, stream>>>(x, node_w, node_b, h, hf);
    hipMemsetAsync(deg, 0, N_NODES * sizeof(int), stream);
    k_deg<<<(E_TOT + 255) / 256, 256, 0, stream>>>(dst, deg);
    k_invd<<<(N_NODES + 255) / 256, 256, 0, stream>>>(deg, invd);

    for (int l = 0; l < NLAYER; ++l) {
        k_edge_mlp<<<E_TOT, 128, 0, stream>>>(ea, e1w + l * F_EDGE * HDIM,
                                              e1b + l * HDIM, efg);
        hipMemsetAsync(agg, 0, (size_t)N_NODES * HDIM * sizeof(float), stream);
        k_msg<<<(E_TOT / 256) * 4, 512, 0, stream>>>(W2F + (size_t)l * 129 * 16384,
                                                     efg, hf, src, dst, agg);
        k_out<<<N_NODES / 16, 128, 0, stream>>>(agg, invd, h,
                                                rw + l * HDIM * HDIM,
                                                cb + l * HDIM, outb);
        k_bn_stats<<<HDIM, 256, 0, stream>>>(outb, mu, rsig);
        k_bn_apply<<<(N_NODES * HDIM) / 256, 256, 0, stream>>>(
            outb, mu, rsig, bng + l * HDIM, bnb + l * HDIM, h, hf);
    }

    hipMemsetAsync(pooled, 0, (size_t)NGRAPH * HDIM * sizeof(float), stream);
    hipMemsetAsync(cnt, 0, NGRAPH * sizeof(int), stream);
    k_pool<<<N_NODES, 128, 0, stream>>>(h, batch, pooled, cnt);
    k_head<<<NGRAPH, 128, 0, stream>>>(pooled, cnt, hw1, hb1, hw2, hb2, y);
}

// Round 2
// 471.272 us; speedup vs baseline: 1.5559x; 1.0485x over previous
//
#include <hip/hip_runtime.h>

// Problem constants
#define N_NODES 4096
#define E_TOT   12288
#define F_NODE  64
#define F_EDGE  16
#define HDIM    128
#define NLAYER  4
#define NGRAPH  256

typedef _Float16 half8 __attribute__((ext_vector_type(8)));
typedef float    f32x4 __attribute__((ext_vector_type(4)));

// ---------------------------------------------------------------------------
// Repack e2_w (+e2_b as a 129th K-chunk) into f16 "fragment-major" layout:
// W2F[((l*129 + k)*32 + chunk)*512 + lane*8 + j]
//   chunk = hc*8 + ot ;  h = hc*32 + (lane>>4)*8 + j ;  o = ot*16 + (lane&15)
// so that global_load_lds(16B/lane) deposits ready-to-use MFMA B fragments.
// ---------------------------------------------------------------------------
__global__ void k_prep_w2(const float* __restrict__ e2w, const float* __restrict__ e2b,
                          _Float16* __restrict__ W2F)
{
    int t = blockIdx.x * 256 + threadIdx.x;
    const int PER_L = 129 * 16384;
    if (t >= NLAYER * PER_L) return;
    int l   = t / PER_L;
    int r   = t - l * PER_L;
    int k   = r >> 14;          // 0..128 (128 = bias chunk)
    int rem = r & 16383;
    int chunk = rem >> 9;
    int lane  = (rem >> 3) & 63;
    int j     = rem & 7;
    int hc = chunk >> 3, ot = chunk & 7;
    int h  = hc * 32 + (lane >> 4) * 8 + j;
    int o  = ot * 16 + (lane & 15);
    float v;
    if (k < 128) v = e2w[((size_t)(l * 128 + k)) * 16384 + h * 128 + o];
    else         v = e2b[(size_t)l * 16384 + h * 128 + o];
    W2F[t] = (_Float16)v;
}

// h = x @ node_w + node_b  (also f16 copy for the gather path)
__global__ __launch_bounds__(128)
void k_node_enc(const float* __restrict__ x, const float* __restrict__ nw,
                const float* __restrict__ nb, float* __restrict__ h,
                _Float16* __restrict__ hf)
{
    __shared__ float xl[F_NODE];
    int n = blockIdx.x, o = threadIdx.x;
    if (o < F_NODE) xl[o] = x[(size_t)n * F_NODE + o];
    __syncthreads();
    float acc = nb[o];
#pragma unroll 8
    for (int f = 0; f < F_NODE; ++f) acc += xl[f] * nw[f * HDIM + o];
    h [(size_t)n * HDIM + o] = acc;
    hf[(size_t)n * HDIM + o] = (_Float16)acc;
}

__global__ void k_deg(const int* __restrict__ dst, int* __restrict__ deg)
{
    int e = blockIdx.x * 256 + threadIdx.x;
    if (e < E_TOT) atomicAdd(&deg[dst[e]], 1);
}

__global__ void k_invd(const int* __restrict__ deg, float* __restrict__ invd)
{
    int n = blockIdx.x * 256 + threadIdx.x;
    if (n < N_NODES) invd[n] = deg[n] > 0 ? 1.0f / (float)deg[n] : 0.0f;
}

// ef = relu(edge_attr @ e1_w[l] + e1_b[l]) stored f16 [E][136] (16B rows;
// col128 = 1.0 bias chunk, cols 129..135 unused)
#define EF_STRIDE 136
__global__ __launch_bounds__(128)
void k_edge_mlp(const float* __restrict__ ea, const float* __restrict__ w1,
                const float* __restrict__ b1, _Float16* __restrict__ efg)
{
    __shared__ float al[F_EDGE];
    int e = blockIdx.x, j = threadIdx.x;
    if (j < F_EDGE) al[j] = ea[(size_t)e * F_EDGE + j];
    __syncthreads();
    float acc = b1[j];
#pragma unroll
    for (int f = 0; f < F_EDGE; ++f) acc += al[f] * w1[f * HDIM + j];
    acc = fmaxf(acc, 0.f);
    efg[(size_t)e * EF_STRIDE + j] = (_Float16)acc;
    if (j == 0) efg[(size_t)e * EF_STRIDE + 128] = (_Float16)1.0f;
}

// ---------------------------------------------------------------------------
// msg[e,o] = sum_k ef[e,k] * (h[src[e],:] @ W2[k,:,:]) ; atomic scatter-add
// into agg4[ks] (per-k-slice partial buffers, merged in k_out).
// v3: BM=96 edges/block, 8 waves (2 row-groups x 4 col-groups), k-split x4
// -> 512 blocks.  LDS = 64KB B double-buffer + 7.5KB efs = 73KB => TWO
// independent blocks per CU (two barrier domains; one computes while the
// other waits).  Counted vmcnt(4), prefetch distance 1.  XCD swizzle keeps
// one k-slice per XCD (L2-resident B).  setprio(1) around MFMA cluster.
// ---------------------------------------------------------------------------
#define BM 96
__global__ __launch_bounds__(512, 4)
void k_msg(const _Float16* __restrict__ W2L,   // layer base: [129][32][512] f16
           const _Float16* __restrict__ efg,   // [E][136] f16
           const _Float16* __restrict__ hf,    // [N][128] f16
           const int* __restrict__ srcIdx,
           const int* __restrict__ dstIdx,
           float* __restrict__ agg4)           // [4][N][128] f32
{
    __shared__ _Float16 Bb[2][16384];   // 2 x 32 KB B-chunk double buffer
    __shared__ _Float16 efs[BM][40];    // local k-slice of ef (<=33 cols + pad)

    const int tid  = threadIdx.x;
    const int lane = tid & 63;
    const int w    = tid >> 6;          // wave 0..7
    const int rq   = w >> 2;            // row-group: 48 edges
    const int ch   = w & 3;             // col-group: 32 outputs
    const int lhi  = lane >> 4;         // 0..3
    const int llo  = lane & 15;

    // XCD-grouped decode (bx%8 -> XCD round-robin): each XCD serves one ks.
    const int bx    = blockIdx.x;
    const int ks    = (bx >> 1) & 3;
    const int tile  = (bx & 1) + (bx >> 3) * 2;   // 0..127
    const int e0    = tile * BM;
    const int kbase = (129 * ks) >> 2;                    // 0,32,64,96
    const int kcnt  = ((129 * (ks + 1)) >> 2) - kbase;    // 32,32,32,33
    float* agg = agg4 + (size_t)ks * N_NODES * HDIM;

    // stage ef k-slice (96 rows x 40 f16), one half8 per thread (480 used)
    if (tid < BM * 5) {
        int r = tid / 5, c = tid - r * 5;
        *(half8*)&efs[r][c * 8] =
            *(const half8*)(efg + (size_t)(e0 + r) * EF_STRIDE + kbase + c * 8);
    }

    // h_src fragments (this wave's 48 rows) resident in registers, f16
    half8 hs[3][4];
#pragma unroll
    for (int rf = 0; rf < 3; ++rf) {
        int s = srcIdx[e0 + rq * 48 + rf * 16 + llo];
        const _Float16* hp = hf + (size_t)s * HDIM + lhi * 8;
#pragma unroll
        for (int hc = 0; hc < 4; ++hc)
            hs[rf][hc] = *(const half8*)(hp + hc * 32);
    }

    // drain all register-bound memory + own efs ds_writes BEFORE staging
    asm volatile("s_waitcnt vmcnt(0) lgkmcnt(0)" ::: "memory");

    // per-k B chunk = 32 KB; wave w stages f16 [w*2048, w*2048+2048) = 4 x 1KB
    auto STAGE = [&](int kg, int buf) {
        const _Float16* g = W2L + (size_t)kg * 16384 + w * 2048 + lane * 8;
        _Float16* lp = &Bb[buf][w * 2048];
#pragma unroll
        for (int i = 0; i < 4; ++i)
            __builtin_amdgcn_global_load_lds(
                (const __attribute__((address_space(1))) void*)(g + i * 512),
                (__attribute__((address_space(3))) void*)(lp + i * 512), 16, 0, 0);
    };

    STAGE(kbase + 0, 0);

    f32x4 acc[3][2];
#pragma unroll
    for (int rf = 0; rf < 3; ++rf)
#pragma unroll
        for (int cf = 0; cf < 2; ++cf)
#pragma unroll
            for (int d = 0; d < 4; ++d) acc[rf][cf][d] = 0.f;

    for (int kk = 0; kk < kcnt; ++kk) {
        const int cur = kk & 1;
        // barrier1: all waves done reading Bb[cur^1] (iter kk-1); kk==0: efs ready
        asm volatile("" ::: "memory");
        __builtin_amdgcn_s_barrier();
        asm volatile("" ::: "memory");
        if (kk + 1 < kcnt) {
            STAGE(kbase + kk + 1, cur ^ 1);
            // wait own stage(kk) 4 loads; stage(kk+1)'s 4 stay in flight
            asm volatile("s_waitcnt vmcnt(4)" ::: "memory");
        } else {
            asm volatile("s_waitcnt vmcnt(0)" ::: "memory");
        }
        asm volatile("" ::: "memory");
        __builtin_amdgcn_s_barrier();
        asm volatile("" ::: "memory");

        // ef scalars for this k (16 rows per rf, broadcast across lhi groups)
        _Float16 efv[3];
#pragma unroll
        for (int rf = 0; rf < 3; ++rf) efv[rf] = efs[rq * 48 + rf * 16 + llo][kk];

        const _Float16* bb = &Bb[cur][ch * 1024 + lane * 8];
        __builtin_amdgcn_s_setprio(1);
#pragma unroll
        for (int hc = 0; hc < 4; ++hc) {
            half8 bfr[2];
#pragma unroll
            for (int cf = 0; cf < 2; ++cf)       // chunk = hc*8 + ch*2 + cf
                bfr[cf] = *(const half8*)(bb + hc * 4096 + cf * 512);
#pragma unroll
            for (int rf = 0; rf < 3; ++rf) {
                half8 av = hs[rf][hc] * efv[rf];   // v_pk_mul_f16
#pragma unroll
                for (int cf = 0; cf < 2; ++cf)
                    acc[rf][cf] = __builtin_amdgcn_mfma_f32_16x16x32_f16(
                        av, bfr[cf], acc[rf][cf], 0, 0, 0);
            }
        }
        __builtin_amdgcn_s_setprio(0);
    }

    // epilogue: scatter-add partial msg into agg[ks][dst]
    // C/D layout: col=lane&15, row=(lane>>4)*4+reg
#pragma unroll
    for (int rf = 0; rf < 3; ++rf) {
#pragma unroll
        for (int r = 0; r < 4; ++r) {
            int row = rq * 48 + rf * 16 + lhi * 4 + r;
            int d   = dstIdx[e0 + row];
#pragma unroll
            for (int cf = 0; cf < 2; ++cf) {
                int o = ch * 32 + cf * 16 + llo;
                atomicAdd(&agg[(size_t)d * HDIM + o], acc[rf][cf][r]);
            }
        }
    }
}

// out = sum_ks agg4*inv_deg + h @ root_w[l] + conv_b[l]   (16 rows per block)
__global__ __launch_bounds__(128)
void k_out(const float* __restrict__ agg4, const float* __restrict__ invd,
           const float* __restrict__ h, const float* __restrict__ rw,
           const float* __restrict__ cb, float* __restrict__ outb)
{
    __shared__ float hl[16][HDIM];
    int n0 = blockIdx.x * 16, o = threadIdx.x;
    for (int r = 0; r < 16; ++r) hl[r][o] = h[(size_t)(n0 + r) * HDIM + o];
    __syncthreads();
    float acc[16];
    float cbv = cb[o];
#pragma unroll
    for (int r = 0; r < 16; ++r) {
        float s = 0.f;
#pragma unroll
        for (int p = 0; p < 4; ++p)
            s += agg4[(size_t)p * N_NODES * HDIM + (size_t)(n0 + r) * HDIM + o];
        acc[r] = s * invd[n0 + r] + cbv;
    }
    for (int hh = 0; hh < HDIM; ++hh) {
        float wv = rw[hh * HDIM + o];
#pragma unroll
        for (int r = 0; r < 16; ++r) acc[r] += hl[r][hh] * wv;
    }
#pragma unroll
    for (int r = 0; r < 16; ++r) outb[(size_t)(n0 + r) * HDIM + o] = acc[r];
}

// per-channel batch stats (biased var) -> mu, rsig
__global__ __launch_bounds__(256)
void k_bn_stats(const float* __restrict__ outb, float* __restrict__ mu,
                float* __restrict__ rsig)
{
    __shared__ float s1[256], s2[256];
    int c = blockIdx.x, t = threadIdx.x;
    float a = 0.f, b = 0.f;
    for (int n = t; n < N_NODES; n += 256) {
        float v = outb[(size_t)n * HDIM + c];
        a += v; b += v * v;
    }
    s1[t] = a; s2[t] = b;
    __syncthreads();
    for (int s = 128; s > 0; s >>= 1) {
        if (t < s) { s1[t] += s1[t + s]; s2[t] += s2[t + s]; }
        __syncthreads();
    }
    if (t == 0) {
        float m   = s1[0] / (float)N_NODES;
        float var = s2[0] / (float)N_NODES - m * m;
        mu[c]   = m;
        rsig[c] = rsqrtf(var + 1e-5f);
    }
}

// h += relu(bn(out));  also refresh f16 copy
__global__ void k_bn_apply(const float* __restrict__ outb, const float* __restrict__ mu,
                           const float* __restrict__ rsig, const float* __restrict__ g,
                           const float* __restrict__ b, float* __restrict__ h,
                           _Float16* __restrict__ hf)
{
    int i = blockIdx.x * 256 + threadIdx.x;   // < N*128
    int o = i & (HDIM - 1);
    float v  = (outb[i] - mu[o]) * rsig[o] * g[o] + b[o];
    float hn = h[i] + fmaxf(v, 0.f);
    h[i]  = hn;
    hf[i] = (_Float16)hn;
}

__global__ __launch_bounds__(128)
void k_pool(const float* __restrict__ h, const int* __restrict__ batch,
            float* __restrict__ pooled, int* __restrict__ cnt)
{
    int n = blockIdx.x, c = threadIdx.x;
    int g = batch[n];
    atomicAdd(&pooled[(size_t)g * HDIM + c], h[(size_t)n * HDIM + c]);
    if (c == 0) atomicAdd(&cnt[g], 1);
}

__global__ __launch_bounds__(128)
void k_head(const float* __restrict__ pooled, const int* __restrict__ cnt,
            const float* __restrict__ w1, const float* __restrict__ b1,
            const float* __restrict__ w2, const float* __restrict__ b2,
            float* __restrict__ y)
{
    __shared__ float pl[HDIM];
    __shared__ float red[HDIM];
    int g = blockIdx.x, o = threadIdx.x;
    float ic = 1.0f / (float)max(cnt[g], 1);
    pl[o] = pooled[(size_t)g * HDIM + o] * ic;
    __syncthreads();
    float t = b1[o];
#pragma unroll 8
    for (int hh = 0; hh < HDIM; ++hh) t += pl[hh] * w1[hh * HDIM + o];
    t = fmaxf(t, 0.f);
    red[o] = t * w2[o];
    __syncthreads();
    for (int s = 64; s > 0; s >>= 1) {
        if (o < s) red[o] += red[o + s];
        __syncthreads();
    }
    if (o == 0) y[g] = red[0] + b2[0];
}

// ---------------------------------------------------------------------------
extern "C" void kernel_launch(void* const* d_in, const int* in_sizes, int n_in,
                              void* d_out, int out_size, void* d_ws, size_t ws_size,
                              hipStream_t stream)
{
    const float* x      = (const float*)d_in[0];
    const int*   ei     = (const int*)  d_in[1];
    const float* ea     = (const float*)d_in[2];
    const int*   batch  = (const int*)  d_in[3];
    const float* node_w = (const float*)d_in[4];
    const float* node_b = (const float*)d_in[5];
    const float* e1w    = (const float*)d_in[6];
    const float* e1b    = (const float*)d_in[7];
    const float* e2w    = (const float*)d_in[8];
    const float* e2b    = (const float*)d_in[9];
    const float* rw     = (const float*)d_in[10];
    const float* cb     = (const float*)d_in[11];
    const float* bng    = (const float*)d_in[12];
    const float* bnb    = (const float*)d_in[13];
    const float* hw1    = (const float*)d_in[14];
    const float* hb1    = (const float*)d_in[15];
    const float* hw2    = (const float*)d_in[16];
    const float* hb2    = (const float*)d_in[17];
    float* y = (float*)d_out;

    // workspace carve-up (~34 MB, all 256B-aligned chunks)
    char* ws = (char*)d_ws;
    _Float16* W2F  = (_Float16*)ws; ws += 16908288;  // 4*129*16384 f16
    float*    h    = (float*)ws;    ws += 2097152;
    _Float16* hf   = (_Float16*)ws; ws += 1048576;
    _Float16* efg  = (_Float16*)ws; ws += 3342336;   // E*136 f16
    float*    agg4 = (float*)ws;    ws += 8388608;   // [4][N][128] f32
    float*    outb = (float*)ws;    ws += 2097152;
    int*      deg  = (int*)ws;      ws += 16384;
    float*    invd = (float*)ws;    ws += 16384;
    float*    mu   = (float*)ws;    ws += 512;
    float*    rsig = (float*)ws;    ws += 512;
    float*    pooled = (float*)ws;  ws += 131072;
    int*      cnt  = (int*)ws;      ws += 1024;

    const int* src = ei;
    const int* dst = ei + E_TOT;

    k_prep_w2<<<33024, 256, 0, stream>>>(e2w, e2b, W2F);
    k_node_enc<<<N_NODES, 128, 0, stream>>>(x, node_w, node_b, h, hf);
    hipMemsetAsync(deg, 0, N_NODES * sizeof(int), stream);
    k_deg<<<(E_TOT + 255) / 256, 256, 0, stream>>>(dst, deg);
    k_invd<<<(N_NODES + 255) / 256, 256, 0, stream>>>(deg, invd);

    for (int l = 0; l < NLAYER; ++l) {
        k_edge_mlp<<<E_TOT, 128, 0, stream>>>(ea, e1w + l * F_EDGE * HDIM,
                                              e1b + l * HDIM, efg);
        hipMemsetAsync(agg4, 0, (size_t)4 * N_NODES * HDIM * sizeof(float), stream);
        k_msg<<<(E_TOT / BM) * 4, 512, 0, stream>>>(W2F + (size_t)l * 129 * 16384,
                                                    efg, hf, src, dst, agg4);
        k_out<<<N_NODES / 16, 128, 0, stream>>>(agg4, invd, h,
                                                rw + l * HDIM * HDIM,
                                                cb + l * HDIM, outb);
        k_bn_stats<<<HDIM, 256, 0, stream>>>(outb, mu, rsig);
        k_bn_apply<<<(N_NODES * HDIM) / 256, 256, 0, stream>>>(
            outb, mu, rsig, bng + l * HDIM, bnb + l * HDIM, h, hf);
    }

    hipMemsetAsync(pooled, 0, (size_t)NGRAPH * HDIM * sizeof(float), stream);
    hipMemsetAsync(cnt, 0, NGRAPH * sizeof(int), stream);
    k_pool<<<N_NODES, 128, 0, stream>>>(h, batch, pooled, cnt);
    k_head<<<NGRAPH, 128, 0, stream>>>(pooled, cnt, hw1, hb1, hw2, hb2, y);
}

// Round 3
// 432.173 us; speedup vs baseline: 1.6967x; 1.0905x over previous
//
#include <hip/hip_runtime.h>

// Problem constants
#define N_NODES 4096
#define E_TOT   12288
#define F_NODE  64
#define F_EDGE  16
#define HDIM    128
#define NLAYER  4
#define NGRAPH  256

typedef _Float16 half8 __attribute__((ext_vector_type(8)));
typedef float    f32x4 __attribute__((ext_vector_type(4)));

// ---------------------------------------------------------------------------
// Repack e2_w (+e2_b as a 129th K-chunk) into f16 "fragment-major" layout:
// W2F[((l*129 + k)*32 + chunk)*512 + lane*8 + j]
//   chunk = hc*8 + ot ;  h = hc*32 + (lane>>4)*8 + j ;  o = ot*16 + (lane&15)
// so a wave's global_load_dwordx4 at (chunk*512 + lane*8) is a ready MFMA
// B fragment (16B/lane, fully coalesced 1KB line).
// ---------------------------------------------------------------------------
__global__ void k_prep_w2(const float* __restrict__ e2w, const float* __restrict__ e2b,
                          _Float16* __restrict__ W2F)
{
    int t = blockIdx.x * 256 + threadIdx.x;
    const int PER_L = 129 * 16384;
    if (t >= NLAYER * PER_L) return;
    int l   = t / PER_L;
    int r   = t - l * PER_L;
    int k   = r >> 14;          // 0..128 (128 = bias chunk)
    int rem = r & 16383;
    int chunk = rem >> 9;
    int lane  = (rem >> 3) & 63;
    int j     = rem & 7;
    int hc = chunk >> 3, ot = chunk & 7;
    int h  = hc * 32 + (lane >> 4) * 8 + j;
    int o  = ot * 16 + (lane & 15);
    float v;
    if (k < 128) v = e2w[((size_t)(l * 128 + k)) * 16384 + h * 128 + o];
    else         v = e2b[(size_t)l * 16384 + h * 128 + o];
    W2F[t] = (_Float16)v;
}

// h = x @ node_w + node_b  (also f16 copy for the gather path)
__global__ __launch_bounds__(128)
void k_node_enc(const float* __restrict__ x, const float* __restrict__ nw,
                const float* __restrict__ nb, float* __restrict__ h,
                _Float16* __restrict__ hf)
{
    __shared__ float xl[F_NODE];
    int n = blockIdx.x, o = threadIdx.x;
    if (o < F_NODE) xl[o] = x[(size_t)n * F_NODE + o];
    __syncthreads();
    float acc = nb[o];
#pragma unroll 8
    for (int f = 0; f < F_NODE; ++f) acc += xl[f] * nw[f * HDIM + o];
    h [(size_t)n * HDIM + o] = acc;
    hf[(size_t)n * HDIM + o] = (_Float16)acc;
}

__global__ void k_deg(const int* __restrict__ dst, int* __restrict__ deg)
{
    int e = blockIdx.x * 256 + threadIdx.x;
    if (e < E_TOT) atomicAdd(&deg[dst[e]], 1);
}

__global__ void k_invd(const int* __restrict__ deg, float* __restrict__ invd)
{
    int n = blockIdx.x * 256 + threadIdx.x;
    if (n < N_NODES) invd[n] = deg[n] > 0 ? 1.0f / (float)deg[n] : 0.0f;
}

// ef = relu(edge_attr @ e1_w[l] + e1_b[l]) stored f16 [E][136] (16B rows;
// col128 = 1.0 bias chunk, cols 129..135 unused).
// v4: 16 edges per block, 256 thr; w1 (8KB) staged in LDS once per block.
#define EF_STRIDE 136
__global__ __launch_bounds__(256)
void k_edge_mlp(const float* __restrict__ ea, const float* __restrict__ w1,
                const float* __restrict__ b1, _Float16* __restrict__ efg)
{
    __shared__ float al[16][17];
    __shared__ float wl[16][HDIM];
    __shared__ float bl[HDIM];
    int t = threadIdx.x, e0 = blockIdx.x * 16;
    if (t < HDIM) bl[t] = b1[t];
    for (int i = t; i < F_EDGE * HDIM; i += 256) wl[i >> 7][i & 127] = w1[i];
    { int i = t; al[i >> 4][i & 15] = ea[(size_t)e0 * F_EDGE + i]; }
    __syncthreads();
    int e = t >> 4, og = t & 15;
    float acc[8];
#pragma unroll
    for (int j = 0; j < 8; ++j) acc[j] = bl[og * 8 + j];
#pragma unroll
    for (int f = 0; f < F_EDGE; ++f) {
        float a = al[e][f];
#pragma unroll
        for (int j = 0; j < 8; ++j) acc[j] += a * wl[f][og * 8 + j];
    }
    half8 o;
#pragma unroll
    for (int j = 0; j < 8; ++j) o[j] = (_Float16)fmaxf(acc[j], 0.f);
    *(half8*)&efg[(size_t)(e0 + e) * EF_STRIDE + og * 8] = o;
    if (og == 0) efg[(size_t)(e0 + e) * EF_STRIDE + 128] = (_Float16)1.0f;
}

// ---------------------------------------------------------------------------
// msg[e,o] = sum_k ef[e,k] * (h[src[e],:] @ W2[k,:,:]) ; atomic scatter-add
// into agg4[ks] (per-k-slice partials, merged in k_out).
// v4: BARRIER-FREE register streaming.  BM=64 edges/block, 256 thr (4 waves),
// each wave owns all 64 rows x 32 cols.  B fragments load straight from L2
// into VGPRs (compiler-scoreboarded counted vmcnt), double-buffered at
// half-k granularity -> no LDS for B, no in-loop barriers at all.
// k-split x4, ks-grouped per XCD (1.06MB W2 slice L2-resident).
// 768 blocks x 3/CU = exactly one resident round (12 waves/CU free-running).
// ---------------------------------------------------------------------------
#define BM 64
__global__ __launch_bounds__(256, 3)
void k_msg(const _Float16* __restrict__ W2L,   // layer base: [129][32][512] f16
           const _Float16* __restrict__ efg,   // [E][136] f16
           const _Float16* __restrict__ hf,    // [N][128] f16
           const int* __restrict__ srcIdx,
           const int* __restrict__ dstIdx,
           float* __restrict__ agg4)           // [4][N][128] f32
{
    __shared__ _Float16 efs[BM][40];    // local k-slice of ef (<=33 cols + pad)

    const int tid  = threadIdx.x;
    const int lane = tid & 63;
    const int w    = tid >> 6;          // wave 0..3, owns cols [w*32, w*32+32)
    const int lhi  = lane >> 4;         // 0..3
    const int llo  = lane & 15;

    // XCD-grouped decode: bx%8 -> XCD; XCD pair {2ks,2ks+1} serves k-slice ks.
    const int bx    = blockIdx.x;
    const int ks    = (bx & 7) >> 1;
    const int tile  = (bx >> 3) * 2 + (bx & 1);   // 0..191
    const int e0    = tile * BM;
    const int kbase = (129 * ks) >> 2;                    // 0,32,64,96
    const int kcnt  = ((129 * (ks + 1)) >> 2) - kbase;    // 32,32,32,33
    float* agg = agg4 + (size_t)ks * N_NODES * HDIM;

    // stage ef k-slice (64 rows x 5 half8)
    for (int i = tid; i < BM * 5; i += 256) {
        int r = i / 5, c = i - r * 5;
        *(half8*)&efs[r][c * 8] =
            *(const half8*)(efg + (size_t)(e0 + r) * EF_STRIDE + kbase + c * 8);
    }

    // h_src fragments (all 64 rows; every wave needs all rows) in registers
    half8 hs[4][4];
#pragma unroll
    for (int rf = 0; rf < 4; ++rf) {
        int s = srcIdx[e0 + rf * 16 + llo];
        const _Float16* hp = hf + (size_t)s * HDIM + lhi * 8;
#pragma unroll
        for (int hc = 0; hc < 4; ++hc)
            hs[rf][hc] = *(const half8*)(hp + hc * 32);
    }

    __syncthreads();   // efs ready (only barrier in the kernel)

    // B fragment base: chunk = hc*8 + w*2 + cf ; offsets in f16 units:
    //   (kk)*16384 + hc*4096 + cf*512, lane offset lane*8 (16B/lane)
    const _Float16* bp = W2L + (size_t)kbase * 16384 + (w * 2) * 512 + lane * 8;

#define LDH(dst, kk, h2) do {                                          \
        const _Float16* p_ = bp + (size_t)(kk) * 16384 + (h2) * 8192;  \
        dst[0] = *(const half8*)(p_);                                  \
        dst[1] = *(const half8*)(p_ + 512);                            \
        dst[2] = *(const half8*)(p_ + 4096);                           \
        dst[3] = *(const half8*)(p_ + 4608);                           \
    } while (0)

    half8 B0[4], B1[4];
    LDH(B0, 0, 0);      // (k=0, hc 0-1) fragments
    LDH(B1, 0, 1);      // (k=0, hc 2-3) fragments

    f32x4 acc[4][2];
#pragma unroll
    for (int rf = 0; rf < 4; ++rf)
#pragma unroll
        for (int cf = 0; cf < 2; ++cf)
#pragma unroll
            for (int d = 0; d < 4; ++d) acc[rf][cf][d] = 0.f;

    for (int kk = 0; kk < kcnt; ++kk) {
        _Float16 efv[4];
#pragma unroll
        for (int rf = 0; rf < 4; ++rf) efv[rf] = efs[rf * 16 + llo][kk];

        // half 0: hc 0-1 from B0 (compiler inserts counted vmcnt before use)
#pragma unroll
        for (int rf = 0; rf < 4; ++rf) {
            half8 av0 = hs[rf][0] * efv[rf];
            half8 av1 = hs[rf][1] * efv[rf];
            acc[rf][0] = __builtin_amdgcn_mfma_f32_16x16x32_f16(av0, B0[0], acc[rf][0], 0, 0, 0);
            acc[rf][1] = __builtin_amdgcn_mfma_f32_16x16x32_f16(av0, B0[1], acc[rf][1], 0, 0, 0);
            acc[rf][0] = __builtin_amdgcn_mfma_f32_16x16x32_f16(av1, B0[2], acc[rf][0], 0, 0, 0);
            acc[rf][1] = __builtin_amdgcn_mfma_f32_16x16x32_f16(av1, B0[3], acc[rf][1], 0, 0, 0);
        }
        if (kk + 1 < kcnt) LDH(B0, kk + 1, 0);   // refill right after last use

        // half 1: hc 2-3 from B1
#pragma unroll
        for (int rf = 0; rf < 4; ++rf) {
            half8 av2 = hs[rf][2] * efv[rf];
            half8 av3 = hs[rf][3] * efv[rf];
            acc[rf][0] = __builtin_amdgcn_mfma_f32_16x16x32_f16(av2, B1[0], acc[rf][0], 0, 0, 0);
            acc[rf][1] = __builtin_amdgcn_mfma_f32_16x16x32_f16(av2, B1[1], acc[rf][1], 0, 0, 0);
            acc[rf][0] = __builtin_amdgcn_mfma_f32_16x16x32_f16(av3, B1[2], acc[rf][0], 0, 0, 0);
            acc[rf][1] = __builtin_amdgcn_mfma_f32_16x16x32_f16(av3, B1[3], acc[rf][1], 0, 0, 0);
        }
        if (kk + 1 < kcnt) LDH(B1, kk + 1, 1);
    }
#undef LDH

    // epilogue: scatter-add partial msg into agg[ks][dst]
    // C/D layout: col=lane&15, row=(lane>>4)*4+reg
#pragma unroll
    for (int rf = 0; rf < 4; ++rf) {
#pragma unroll
        for (int r = 0; r < 4; ++r) {
            int row = rf * 16 + lhi * 4 + r;
            int d   = dstIdx[e0 + row];
#pragma unroll
            for (int cf = 0; cf < 2; ++cf) {
                int o = w * 32 + cf * 16 + llo;
                atomicAdd(&agg[(size_t)d * HDIM + o], acc[rf][cf][r]);
            }
        }
    }
}

// out = sum_ks agg4*inv_deg + h @ root_w[l] + conv_b[l]   (16 rows per block)
// also accumulates per-channel batch sum / sumsq for BN (fused k_bn_stats).
__global__ __launch_bounds__(128)
void k_out(const float* __restrict__ agg4, const float* __restrict__ invd,
           const float* __restrict__ h, const float* __restrict__ rw,
           const float* __restrict__ cb, float* __restrict__ outb,
           float* __restrict__ bns1, float* __restrict__ bns2)
{
    __shared__ float hl[16][HDIM];
    int n0 = blockIdx.x * 16, o = threadIdx.x;
    for (int r = 0; r < 16; ++r) hl[r][o] = h[(size_t)(n0 + r) * HDIM + o];
    __syncthreads();
    float acc[16];
    float cbv = cb[o];
#pragma unroll
    for (int r = 0; r < 16; ++r) {
        float s = 0.f;
#pragma unroll
        for (int p = 0; p < 4; ++p)
            s += agg4[(size_t)p * N_NODES * HDIM + (size_t)(n0 + r) * HDIM + o];
        acc[r] = s * invd[n0 + r] + cbv;
    }
    for (int hh = 0; hh < HDIM; ++hh) {
        float wv = rw[hh * HDIM + o];
#pragma unroll
        for (int r = 0; r < 16; ++r) acc[r] += hl[r][hh] * wv;
    }
    float s1 = 0.f, s2 = 0.f;
#pragma unroll
    for (int r = 0; r < 16; ++r) {
        outb[(size_t)(n0 + r) * HDIM + o] = acc[r];
        s1 += acc[r];
        s2 += acc[r] * acc[r];
    }
    atomicAdd(&bns1[o], s1);
    atomicAdd(&bns2[o], s2);
}

// h += relu(bn(out)) with mu/rsig derived inline from fused sums; refresh hf
__global__ void k_bn_apply(const float* __restrict__ outb, const float* __restrict__ bns1,
                           const float* __restrict__ bns2, const float* __restrict__ g,
                           const float* __restrict__ b, float* __restrict__ h,
                           _Float16* __restrict__ hf)
{
    int i = blockIdx.x * 256 + threadIdx.x;   // < N*128
    int o = i & (HDIM - 1);
    const float inv_n = 1.0f / (float)N_NODES;
    float m   = bns1[o] * inv_n;
    float var = bns2[o] * inv_n - m * m;
    float rs  = rsqrtf(var + 1e-5f);
    float v  = (outb[i] - m) * rs * g[o] + b[o];
    float hn = h[i] + fmaxf(v, 0.f);
    h[i]  = hn;
    hf[i] = (_Float16)hn;
}

__global__ __launch_bounds__(128)
void k_pool(const float* __restrict__ h, const int* __restrict__ batch,
            float* __restrict__ pooled, int* __restrict__ cnt)
{
    int n = blockIdx.x, c = threadIdx.x;
    int g = batch[n];
    atomicAdd(&pooled[(size_t)g * HDIM + c], h[(size_t)n * HDIM + c]);
    if (c == 0) atomicAdd(&cnt[g], 1);
}

__global__ __launch_bounds__(128)
void k_head(const float* __restrict__ pooled, const int* __restrict__ cnt,
            const float* __restrict__ w1, const float* __restrict__ b1,
            const float* __restrict__ w2, const float* __restrict__ b2,
            float* __restrict__ y)
{
    __shared__ float pl[HDIM];
    __shared__ float red[HDIM];
    int g = blockIdx.x, o = threadIdx.x;
    float ic = 1.0f / (float)max(cnt[g], 1);
    pl[o] = pooled[(size_t)g * HDIM + o] * ic;
    __syncthreads();
    float t = b1[o];
#pragma unroll 8
    for (int hh = 0; hh < HDIM; ++hh) t += pl[hh] * w1[hh * HDIM + o];
    t = fmaxf(t, 0.f);
    red[o] = t * w2[o];
    __syncthreads();
    for (int s = 64; s > 0; s >>= 1) {
        if (o < s) red[o] += red[o + s];
        __syncthreads();
    }
    if (o == 0) y[g] = red[0] + b2[0];
}

// ---------------------------------------------------------------------------
extern "C" void kernel_launch(void* const* d_in, const int* in_sizes, int n_in,
                              void* d_out, int out_size, void* d_ws, size_t ws_size,
                              hipStream_t stream)
{
    const float* x      = (const float*)d_in[0];
    const int*   ei     = (const int*)  d_in[1];
    const float* ea     = (const float*)d_in[2];
    const int*   batch  = (const int*)  d_in[3];
    const float* node_w = (const float*)d_in[4];
    const float* node_b = (const float*)d_in[5];
    const float* e1w    = (const float*)d_in[6];
    const float* e1b    = (const float*)d_in[7];
    const float* e2w    = (const float*)d_in[8];
    const float* e2b    = (const float*)d_in[9];
    const float* rw     = (const float*)d_in[10];
    const float* cb     = (const float*)d_in[11];
    const float* bng    = (const float*)d_in[12];
    const float* bnb    = (const float*)d_in[13];
    const float* hw1    = (const float*)d_in[14];
    const float* hb1    = (const float*)d_in[15];
    const float* hw2    = (const float*)d_in[16];
    const float* hb2    = (const float*)d_in[17];
    float* y = (float*)d_out;

    // workspace carve-up (~34 MB, all 256B-aligned chunks)
    char* ws = (char*)d_ws;
    _Float16* W2F  = (_Float16*)ws; ws += 16908288;  // 4*129*16384 f16
    float*    h    = (float*)ws;    ws += 2097152;
    _Float16* hf   = (_Float16*)ws; ws += 1048576;
    _Float16* efg  = (_Float16*)ws; ws += 3342336;   // E*136 f16
    float*    agg4 = (float*)ws;    ws += 8388608;   // [4][N][128] f32
    float*    bns1 = (float*)ws;    ws += 512;       // BN sum   (memset w/ agg4)
    float*    bns2 = (float*)ws;    ws += 512;       // BN sumsq (memset w/ agg4)
    float*    outb = (float*)ws;    ws += 2097152;
    int*      deg  = (int*)ws;      ws += 16384;
    float*    invd = (float*)ws;    ws += 16384;
    float*    pooled = (float*)ws;  ws += 131072;
    int*      cnt  = (int*)ws;      ws += 1024;

    const int* src = ei;
    const int* dst = ei + E_TOT;

    k_prep_w2<<<33024, 256, 0, stream>>>(e2w, e2b, W2F);
    k_node_enc<<<N_NODES, 128, 0, stream>>>(x, node_w, node_b, h, hf);
    hipMemsetAsync(deg, 0, N_NODES * sizeof(int), stream);
    k_deg<<<(E_TOT + 255) / 256, 256, 0, stream>>>(dst, deg);
    k_invd<<<(N_NODES + 255) / 256, 256, 0, stream>>>(deg, invd);

    for (int l = 0; l < NLAYER; ++l) {
        k_edge_mlp<<<E_TOT / 16, 256, 0, stream>>>(ea, e1w + l * F_EDGE * HDIM,
                                                   e1b + l * HDIM, efg);
        // one memset covers agg4 + bns1 + bns2 (contiguous)
        hipMemsetAsync(agg4, 0, (size_t)4 * N_NODES * HDIM * sizeof(float) + 1024, stream);
        k_msg<<<(E_TOT / BM) * 4, 256, 0, stream>>>(W2F + (size_t)l * 129 * 16384,
                                                    efg, hf, src, dst, agg4);
        k_out<<<N_NODES / 16, 128, 0, stream>>>(agg4, invd, h,
                                                rw + l * HDIM * HDIM,
                                                cb + l * HDIM, outb, bns1, bns2);
        k_bn_apply<<<(N_NODES * HDIM) / 256, 256, 0, stream>>>(
            outb, bns1, bns2, bng + l * HDIM, bnb + l * HDIM, h, hf);
    }

    hipMemsetAsync(pooled, 0, (size_t)NGRAPH * HDIM * sizeof(float), stream);
    hipMemsetAsync(cnt, 0, NGRAPH * sizeof(int), stream);
    k_pool<<<N_NODES, 128, 0, stream>>>(h, batch, pooled, cnt);
    k_head<<<NGRAPH, 128, 0, stream>>>(pooled, cnt, hw1, hb1, hw2, hb2, y);
}

// Round 4
// 416.538 us; speedup vs baseline: 1.7604x; 1.0375x over previous
//
#include <hip/hip_runtime.h>

// Problem constants
#define N_NODES 4096
#define E_TOT   12288
#define F_NODE  64
#define F_EDGE  16
#define HDIM    128
#define NLAYER  4
#define NGRAPH  256

typedef _Float16 half8 __attribute__((ext_vector_type(8)));
typedef float    f32x4 __attribute__((ext_vector_type(4)));

// ---------------------------------------------------------------------------
// Repack e2_w (+e2_b as a 129th K-chunk) into f16 "fragment-major" layout:
// W2F[((l*129 + k)*32 + chunk)*512 + lane*8 + j]
//   chunk = hc*8 + ot ;  h = hc*32 + (lane>>4)*8 + j ;  o = ot*16 + (lane&15)
// so a wave's global_load_dwordx4 at (chunk*512 + lane*8) is a ready MFMA
// B fragment (16B/lane, fully coalesced 1KB line).
// ---------------------------------------------------------------------------
__global__ void k_prep_w2(const float* __restrict__ e2w, const float* __restrict__ e2b,
                          _Float16* __restrict__ W2F)
{
    int t = blockIdx.x * 256 + threadIdx.x;
    const int PER_L = 129 * 16384;
    if (t >= NLAYER * PER_L) return;
    int l   = t / PER_L;
    int r   = t - l * PER_L;
    int k   = r >> 14;          // 0..128 (128 = bias chunk)
    int rem = r & 16383;
    int chunk = rem >> 9;
    int lane  = (rem >> 3) & 63;
    int j     = rem & 7;
    int hc = chunk >> 3, ot = chunk & 7;
    int h  = hc * 32 + (lane >> 4) * 8 + j;
    int o  = ot * 16 + (lane & 15);
    float v;
    if (k < 128) v = e2w[((size_t)(l * 128 + k)) * 16384 + h * 128 + o];
    else         v = e2b[(size_t)l * 16384 + h * 128 + o];
    W2F[t] = (_Float16)v;
}

// h = x @ node_w + node_b  (also f16 copy for the gather path)
__global__ __launch_bounds__(128)
void k_node_enc(const float* __restrict__ x, const float* __restrict__ nw,
                const float* __restrict__ nb, float* __restrict__ h,
                _Float16* __restrict__ hf)
{
    __shared__ float xl[F_NODE];
    int n = blockIdx.x, o = threadIdx.x;
    if (o < F_NODE) xl[o] = x[(size_t)n * F_NODE + o];
    __syncthreads();
    float acc = nb[o];
#pragma unroll 8
    for (int f = 0; f < F_NODE; ++f) acc += xl[f] * nw[f * HDIM + o];
    h [(size_t)n * HDIM + o] = acc;
    hf[(size_t)n * HDIM + o] = (_Float16)acc;
}

__global__ void k_deg(const int* __restrict__ dst, int* __restrict__ deg)
{
    int e = blockIdx.x * 256 + threadIdx.x;
    if (e < E_TOT) atomicAdd(&deg[dst[e]], 1);
}

__global__ void k_invd(const int* __restrict__ deg, float* __restrict__ invd)
{
    int n = blockIdx.x * 256 + threadIdx.x;
    if (n < N_NODES) invd[n] = deg[n] > 0 ? 1.0f / (float)deg[n] : 0.0f;
}

// ef = relu(edge_attr @ e1_w[l] + e1_b[l]) stored f16 [E][136] (16B rows;
// col128 = 1.0 bias chunk, cols 129..135 unused).
// 16 edges per block, 256 thr; w1 (8KB) staged in LDS once per block.
#define EF_STRIDE 136
__global__ __launch_bounds__(256)
void k_edge_mlp(const float* __restrict__ ea, const float* __restrict__ w1,
                const float* __restrict__ b1, _Float16* __restrict__ efg)
{
    __shared__ float al[16][17];
    __shared__ float wl[16][HDIM];
    __shared__ float bl[HDIM];
    int t = threadIdx.x, e0 = blockIdx.x * 16;
    if (t < HDIM) bl[t] = b1[t];
    for (int i = t; i < F_EDGE * HDIM; i += 256) wl[i >> 7][i & 127] = w1[i];
    { int i = t; al[i >> 4][i & 15] = ea[(size_t)e0 * F_EDGE + i]; }
    __syncthreads();
    int e = t >> 4, og = t & 15;
    float acc[8];
#pragma unroll
    for (int j = 0; j < 8; ++j) acc[j] = bl[og * 8 + j];
#pragma unroll
    for (int f = 0; f < F_EDGE; ++f) {
        float a = al[e][f];
#pragma unroll
        for (int j = 0; j < 8; ++j) acc[j] += a * wl[f][og * 8 + j];
    }
    half8 o;
#pragma unroll
    for (int j = 0; j < 8; ++j) o[j] = (_Float16)fmaxf(acc[j], 0.f);
    *(half8*)&efg[(size_t)(e0 + e) * EF_STRIDE + og * 8] = o;
    if (og == 0) efg[(size_t)(e0 + e) * EF_STRIDE + 128] = (_Float16)1.0f;
}

// ---------------------------------------------------------------------------
// msg[e,o] = sum_k ef[e,k] * (h[src[e],:] @ W2[k,:,:]) ; atomic scatter-add
// into single agg (k-split partials merge via the atomics).
// v5: barrier-free register streaming, QUARTER-staggered B refill: each
// hc-quarter's fragment pair is refilled for k+1 right after its last use in
// iter k -> prefetch distance = 3/4 iteration (~315 cyc > L2 latency) at the
// SAME register cost as the half scheme.  efv ds_reads software-pipelined
// one iteration ahead.  k-split x4, ks-grouped per XCD (L2-resident W2
// slice).  768 blocks x 3/CU = exactly one resident round.
// Block 0 additionally zeroes bns1/bns2 for the following k_out.
// ---------------------------------------------------------------------------
#define BM 64
__global__ __launch_bounds__(256, 3)
void k_msg(const _Float16* __restrict__ W2L,   // layer base: [129][32][512] f16
           const _Float16* __restrict__ efg,   // [E][136] f16
           const _Float16* __restrict__ hf,    // [N][128] f16
           const int* __restrict__ srcIdx,
           const int* __restrict__ dstIdx,
           float* __restrict__ agg,            // [N][128] f32
           float* __restrict__ bns1,
           float* __restrict__ bns2)
{
    __shared__ _Float16 efs[BM][40];    // local k-slice of ef (<=33 cols + pad)

    const int tid  = threadIdx.x;
    const int lane = tid & 63;
    const int w    = tid >> 6;          // wave 0..3, owns cols [w*32, w*32+32)
    const int lhi  = lane >> 4;         // 0..3
    const int llo  = lane & 15;

    // XCD-grouped decode: bx%8 -> XCD; XCD pair {2ks,2ks+1} serves k-slice ks.
    const int bx    = blockIdx.x;
    const int ks    = (bx & 7) >> 1;
    const int tile  = (bx >> 3) * 2 + (bx & 1);   // 0..191
    const int e0    = tile * BM;
    const int kbase = (129 * ks) >> 2;                    // 0,32,64,96
    const int kcnt  = ((129 * (ks + 1)) >> 2) - kbase;    // 32,32,32,33

    // zero BN partial sums for the k_out that follows (stream-ordered)
    if (bx == 0) {
        if (tid < HDIM)            bns1[tid] = 0.f;
        else if (tid < 2 * HDIM)   bns2[tid - HDIM] = 0.f;
    }

    // stage ef k-slice (64 rows x 5 half8)
    for (int i = tid; i < BM * 5; i += 256) {
        int r = i / 5, c = i - r * 5;
        *(half8*)&efs[r][c * 8] =
            *(const half8*)(efg + (size_t)(e0 + r) * EF_STRIDE + kbase + c * 8);
    }

    // h_src fragments (all 64 rows; every wave needs all rows) in registers
    half8 hs[4][4];
#pragma unroll
    for (int rf = 0; rf < 4; ++rf) {
        int s = srcIdx[e0 + rf * 16 + llo];
        const _Float16* hp = hf + (size_t)s * HDIM + lhi * 8;
#pragma unroll
        for (int hc = 0; hc < 4; ++hc)
            hs[rf][hc] = *(const half8*)(hp + hc * 32);
    }

    __syncthreads();   // efs ready (only barrier in the kernel)

    // B fragment (hc, cf) at bp + kk*16384 + hc*4096 + cf*512 (f16 units)
    const _Float16* bp = W2L + (size_t)kbase * 16384 + (w * 2) * 512 + lane * 8;

#define LDQ(d0, d1, kk, hc) do {                                            \
        const _Float16* p_ = bp + (size_t)(kk) * 16384 + (hc) * 4096;       \
        d0 = *(const half8*)(p_); d1 = *(const half8*)(p_ + 512);           \
    } while (0)

    half8 b00, b01, b10, b11, b20, b21, b30, b31;
    LDQ(b00, b01, 0, 0);
    LDQ(b10, b11, 0, 1);
    LDQ(b20, b21, 0, 2);
    LDQ(b30, b31, 0, 3);

    f32x4 acc[4][2];
#pragma unroll
    for (int rf = 0; rf < 4; ++rf)
#pragma unroll
        for (int cf = 0; cf < 2; ++cf)
#pragma unroll
            for (int d = 0; d < 4; ++d) acc[rf][cf][d] = 0.f;

    _Float16 efc[4];
#pragma unroll
    for (int rf = 0; rf < 4; ++rf) efc[rf] = efs[rf * 16 + llo][0];

    for (int kk = 0; kk < kcnt; ++kk) {
        const bool nx = (kk + 1 < kcnt);
        // next iteration's ef scalars (ds latency hidden under this iter)
        _Float16 efn[4];
        const int kn = nx ? kk + 1 : kk;
#pragma unroll
        for (int rf = 0; rf < 4; ++rf) efn[rf] = efs[rf * 16 + llo][kn];

        // quarter hc=0
#pragma unroll
        for (int rf = 0; rf < 4; ++rf) {
            half8 av = hs[rf][0] * efc[rf];
            acc[rf][0] = __builtin_amdgcn_mfma_f32_16x16x32_f16(av, b00, acc[rf][0], 0, 0, 0);
            acc[rf][1] = __builtin_amdgcn_mfma_f32_16x16x32_f16(av, b01, acc[rf][1], 0, 0, 0);
        }
        if (nx) LDQ(b00, b01, kk + 1, 0);

        // quarter hc=1
#pragma unroll
        for (int rf = 0; rf < 4; ++rf) {
            half8 av = hs[rf][1] * efc[rf];
            acc[rf][0] = __builtin_amdgcn_mfma_f32_16x16x32_f16(av, b10, acc[rf][0], 0, 0, 0);
            acc[rf][1] = __builtin_amdgcn_mfma_f32_16x16x32_f16(av, b11, acc[rf][1], 0, 0, 0);
        }
        if (nx) LDQ(b10, b11, kk + 1, 1);

        // quarter hc=2
#pragma unroll
        for (int rf = 0; rf < 4; ++rf) {
            half8 av = hs[rf][2] * efc[rf];
            acc[rf][0] = __builtin_amdgcn_mfma_f32_16x16x32_f16(av, b20, acc[rf][0], 0, 0, 0);
            acc[rf][1] = __builtin_amdgcn_mfma_f32_16x16x32_f16(av, b21, acc[rf][1], 0, 0, 0);
        }
        if (nx) LDQ(b20, b21, kk + 1, 2);

        // quarter hc=3
#pragma unroll
        for (int rf = 0; rf < 4; ++rf) {
            half8 av = hs[rf][3] * efc[rf];
            acc[rf][0] = __builtin_amdgcn_mfma_f32_16x16x32_f16(av, b30, acc[rf][0], 0, 0, 0);
            acc[rf][1] = __builtin_amdgcn_mfma_f32_16x16x32_f16(av, b31, acc[rf][1], 0, 0, 0);
        }
        if (nx) LDQ(b30, b31, kk + 1, 3);

#pragma unroll
        for (int rf = 0; rf < 4; ++rf) efc[rf] = efn[rf];
    }
#undef LDQ

    // epilogue: scatter-add partial msg into agg[dst]
    // C/D layout: col=lane&15, row=(lane>>4)*4+reg
#pragma unroll
    for (int rf = 0; rf < 4; ++rf) {
#pragma unroll
        for (int r = 0; r < 4; ++r) {
            int row = rf * 16 + lhi * 4 + r;
            int d   = dstIdx[e0 + row];
#pragma unroll
            for (int cf = 0; cf < 2; ++cf) {
                int o = w * 32 + cf * 16 + llo;
                atomicAdd(&agg[(size_t)d * HDIM + o], acc[rf][cf][r]);
            }
        }
    }
}

// out = agg*inv_deg + h @ root_w[l] + conv_b[l]   (16 rows per block)
// also accumulates per-channel batch sum / sumsq for BN (fused bn_stats).
__global__ __launch_bounds__(128)
void k_out(const float* __restrict__ agg, const float* __restrict__ invd,
           const float* __restrict__ h, const float* __restrict__ rw,
           const float* __restrict__ cb, float* __restrict__ outb,
           float* __restrict__ bns1, float* __restrict__ bns2)
{
    __shared__ float hl[16][HDIM];
    int n0 = blockIdx.x * 16, o = threadIdx.x;
    for (int r = 0; r < 16; ++r) hl[r][o] = h[(size_t)(n0 + r) * HDIM + o];
    __syncthreads();
    float acc[16];
    float cbv = cb[o];
#pragma unroll
    for (int r = 0; r < 16; ++r)
        acc[r] = agg[(size_t)(n0 + r) * HDIM + o] * invd[n0 + r] + cbv;
    for (int hh = 0; hh < HDIM; ++hh) {
        float wv = rw[hh * HDIM + o];
#pragma unroll
        for (int r = 0; r < 16; ++r) acc[r] += hl[r][hh] * wv;
    }
    float s1 = 0.f, s2 = 0.f;
#pragma unroll
    for (int r = 0; r < 16; ++r) {
        outb[(size_t)(n0 + r) * HDIM + o] = acc[r];
        s1 += acc[r];
        s2 += acc[r] * acc[r];
    }
    atomicAdd(&bns1[o], s1);
    atomicAdd(&bns2[o], s2);
}

// h += relu(bn(out)) with mu/rsig derived inline; refresh hf.
// Non-last layers: zero agg for the next layer's atomics.
// Last layer: fused global-mean-pool scatter (replaces k_pool).
__global__ void k_bn_apply(const float* __restrict__ outb, const float* __restrict__ bns1,
                           const float* __restrict__ bns2, const float* __restrict__ g,
                           const float* __restrict__ b, float* __restrict__ h,
                           _Float16* __restrict__ hf, float* __restrict__ agg,
                           const int* __restrict__ batch, float* __restrict__ pooled,
                           int* __restrict__ cnt, int last)
{
    int i = blockIdx.x * 256 + threadIdx.x;   // < N*128
    int o = i & (HDIM - 1);
    const float inv_n = 1.0f / (float)N_NODES;
    float m   = bns1[o] * inv_n;
    float var = bns2[o] * inv_n - m * m;
    float rs  = rsqrtf(var + 1e-5f);
    float v  = (outb[i] - m) * rs * g[o] + b[o];
    float hn = h[i] + fmaxf(v, 0.f);
    h[i]  = hn;
    hf[i] = (_Float16)hn;
    if (!last) {
        agg[i] = 0.f;
    } else {
        int n  = i >> 7;
        int gg = batch[n];
        atomicAdd(&pooled[(size_t)gg * HDIM + o], hn);
        if (o == 0) atomicAdd(&cnt[gg], 1);
    }
}

__global__ __launch_bounds__(128)
void k_head(const float* __restrict__ pooled, const int* __restrict__ cnt,
            const float* __restrict__ w1, const float* __restrict__ b1,
            const float* __restrict__ w2, const float* __restrict__ b2,
            float* __restrict__ y)
{
    __shared__ float pl[HDIM];
    __shared__ float red[HDIM];
    int g = blockIdx.x, o = threadIdx.x;
    float ic = 1.0f / (float)max(cnt[g], 1);
    pl[o] = pooled[(size_t)g * HDIM + o] * ic;
    __syncthreads();
    float t = b1[o];
#pragma unroll 8
    for (int hh = 0; hh < HDIM; ++hh) t += pl[hh] * w1[hh * HDIM + o];
    t = fmaxf(t, 0.f);
    red[o] = t * w2[o];
    __syncthreads();
    for (int s = 64; s > 0; s >>= 1) {
        if (o < s) red[o] += red[o + s];
        __syncthreads();
    }
    if (o == 0) y[g] = red[0] + b2[0];
}

// ---------------------------------------------------------------------------
extern "C" void kernel_launch(void* const* d_in, const int* in_sizes, int n_in,
                              void* d_out, int out_size, void* d_ws, size_t ws_size,
                              hipStream_t stream)
{
    const float* x      = (const float*)d_in[0];
    const int*   ei     = (const int*)  d_in[1];
    const float* ea     = (const float*)d_in[2];
    const int*   batch  = (const int*)  d_in[3];
    const float* node_w = (const float*)d_in[4];
    const float* node_b = (const float*)d_in[5];
    const float* e1w    = (const float*)d_in[6];
    const float* e1b    = (const float*)d_in[7];
    const float* e2w    = (const float*)d_in[8];
    const float* e2b    = (const float*)d_in[9];
    const float* rw     = (const float*)d_in[10];
    const float* cb     = (const float*)d_in[11];
    const float* bng    = (const float*)d_in[12];
    const float* bnb    = (const float*)d_in[13];
    const float* hw1    = (const float*)d_in[14];
    const float* hb1    = (const float*)d_in[15];
    const float* hw2    = (const float*)d_in[16];
    const float* hb2    = (const float*)d_in[17];
    float* y = (float*)d_out;

    // workspace carve-up (~27.8 MB, all 256B-aligned chunks)
    char* ws = (char*)d_ws;
    _Float16* W2F  = (_Float16*)ws; ws += 16908288;  // 4*129*16384 f16
    float*    h    = (float*)ws;    ws += 2097152;
    _Float16* hf   = (_Float16*)ws; ws += 1048576;
    _Float16* efg  = (_Float16*)ws; ws += 3342336;   // E*136 f16
    float*    agg  = (float*)ws;    ws += 2097152;   // [N][128] f32
    float*    bns1 = (float*)ws;    ws += 512;       // BN sum
    float*    bns2 = (float*)ws;    ws += 512;       // BN sumsq
    float*    outb = (float*)ws;    ws += 2097152;
    int*      deg  = (int*)ws;      ws += 16384;
    float*    invd = (float*)ws;    ws += 16384;
    float*    pooled = (float*)ws;  ws += 131072;
    int*      cnt  = (int*)ws;      ws += 1024;

    const int* src = ei;
    const int* dst = ei + E_TOT;

    k_prep_w2<<<33024, 256, 0, stream>>>(e2w, e2b, W2F);
    k_node_enc<<<N_NODES, 128, 0, stream>>>(x, node_w, node_b, h, hf);
    hipMemsetAsync(deg, 0, N_NODES * sizeof(int), stream);
    k_deg<<<(E_TOT + 255) / 256, 256, 0, stream>>>(dst, deg);
    k_invd<<<(N_NODES + 255) / 256, 256, 0, stream>>>(deg, invd);
    // agg zero for layer 0; pooled+cnt zero (contiguous => one memset)
    hipMemsetAsync(agg, 0, (size_t)N_NODES * HDIM * sizeof(float), stream);
    hipMemsetAsync(pooled, 0, (size_t)NGRAPH * HDIM * sizeof(float) + NGRAPH * sizeof(int), stream);

    for (int l = 0; l < NLAYER; ++l) {
        k_edge_mlp<<<E_TOT / 16, 256, 0, stream>>>(ea, e1w + l * F_EDGE * HDIM,
                                                   e1b + l * HDIM, efg);
        k_msg<<<(E_TOT / BM) * 4, 256, 0, stream>>>(W2F + (size_t)l * 129 * 16384,
                                                    efg, hf, src, dst, agg, bns1, bns2);
        k_out<<<N_NODES / 16, 128, 0, stream>>>(agg, invd, h,
                                                rw + l * HDIM * HDIM,
                                                cb + l * HDIM, outb, bns1, bns2);
        k_bn_apply<<<(N_NODES * HDIM) / 256, 256, 0, stream>>>(
            outb, bns1, bns2, bng + l * HDIM, bnb + l * HDIM, h, hf,
            agg, batch, pooled, cnt, (l == NLAYER - 1) ? 1 : 0);
    }

    k_head<<<NGRAPH, 128, 0, stream>>>(pooled, cnt, hw1, hb1, hw2, hb2, y);
}